// Round 3
// baseline (306.233 us; speedup 1.0000x reference)
//
#include <hip/hip_runtime.h>
#include <hip/hip_bf16.h>
#include <stdint.h>

// Problem constants
#define B_  2
#define T_  2048
#define E_  1024
#define H_  16
#define D_  64
#define BH_ 32   // B_*H_

typedef unsigned short ushort_t;
typedef __attribute__((ext_vector_type(8))) short bfrag;   // 8 bf16 (4 VGPRs) MFMA A/B operand
typedef __attribute__((ext_vector_type(4))) short s16x4;   // 4 bf16 (8B)
typedef __attribute__((ext_vector_type(4))) float f32x4;   // MFMA C/D

__device__ __forceinline__ ushort_t f2b(float f) {  // fp32 -> bf16 (RTNE)
    uint32_t u = __builtin_bit_cast(uint32_t, f);
    u += 0x7fffu + ((u >> 16) & 1u);
    return (ushort_t)(u >> 16);
}
__device__ __forceinline__ float b2f(ushort_t h) {
    return __builtin_bit_cast(float, (uint32_t)h << 16);
}

#if defined(__has_builtin)
#if __has_builtin(__builtin_amdgcn_exp2f)
#define EXP2(x) __builtin_amdgcn_exp2f(x)
#endif
#endif
#ifndef EXP2
__device__ __forceinline__ float hexp2_(float x) {
    float r;
    asm volatile("v_exp_f32 %0, %1\n\ts_nop 1" : "=v"(r) : "v"(x));
    return r;
}
#define EXP2(x) hexp2_(x)
#endif

__device__ __forceinline__ uint32_t cvtpk_bf16(float lo, float hi) {
    uint32_t r;
    asm("v_cvt_pk_bf16_f32 %0, %1, %2" : "=v"(r) : "v"(lo), "v"(hi));
    return r;
}

typedef const __attribute__((address_space(1))) uint8_t* gas_t;
typedef __attribute__((address_space(3))) uint8_t* las_t;
__device__ __forceinline__ void gload_lds16(const void* g, void* l) {
    __builtin_amdgcn_global_load_lds((gas_t)g, (las_t)l, 16, 0, 0);
}

// ---------------- RoPE cos/sin table: cs[t][j] = (cos, sin), t<2048, j<32 ----------------
__global__ __launch_bounds__(256) void rope_table_kernel(float2* __restrict__ cs) {
    int id = blockIdx.x * 256 + threadIdx.x;  // 65536
    int j = id & 31, t = id >> 5;
    float ang = (float)t * expf(-(float)j * 0.2878231366242558f);  // ln(10000)/32
    float s, c;
    sincosf(ang, &s, &c);
    cs[id] = make_float2(c, s);
}

// ---------------- cast x fp32 -> bf16 ----------------
__global__ __launch_bounds__(256) void cast_x_kernel(const float* __restrict__ in, ushort_t* __restrict__ out) {
    int i = (blockIdx.x * 256 + threadIdx.x) * 8;
    float4 a = *(const float4*)(in + i);
    float4 b = *(const float4*)(in + i + 4);
    ushort_t r[8] = {f2b(a.x), f2b(a.y), f2b(a.z), f2b(a.w), f2b(b.x), f2b(b.y), f2b(b.z), f2b(b.w)};
    *(uint4*)(out + i) = *(const uint4*)r;
}

// ------------- transpose+cast: in[R][C] fp32 -> out[C][R] bf16 -------------
__global__ __launch_bounds__(256) void transpose_cast_kernel(const float* __restrict__ in, ushort_t* __restrict__ out,
                                                             int R, int C) {
    __shared__ float tile[32][33];
    int tx = threadIdx.x, ty = threadIdx.y;
    int c0 = blockIdx.x * 32, r0 = blockIdx.y * 32;
#pragma unroll
    for (int i = 0; i < 4; ++i)
        tile[ty + i * 8][tx] = in[(size_t)(r0 + ty + i * 8) * C + c0 + tx];
    __syncthreads();
#pragma unroll
    for (int i = 0; i < 4; ++i)
        out[(size_t)(c0 + ty + i * 8) * R + r0 + tx] = f2b(tile[tx][ty + i * 8]);
}

// ---------------- GEMM1: qkv = x @ w_qkv + b, fused RoPE on q,k ----------------
// q,k -> [BH][T][D] (rotated; q pre-scaled by 1/8*log2e);  v -> TRANSPOSED Vt [BH][D][T]
__global__ __launch_bounds__(256) void gemm_qkv_kernel(const ushort_t* __restrict__ A, const ushort_t* __restrict__ Bt,
                                                       const float* __restrict__ bias, const float2* __restrict__ cstab,
                                                       ushort_t* __restrict__ qw, ushort_t* __restrict__ kw,
                                                       ushort_t* __restrict__ vw) {
    const int K = 1024;
    __shared__ ushort_t As[128 * 32];
    __shared__ ushort_t Bs[128 * 32];
    int tid = threadIdx.x, lane = tid & 63, wid = tid >> 6;
    int bm = blockIdx.y, bn = blockIdx.x;
    int wm = wid >> 1, wn = wid & 1;
    int lm = lane & 15, lg = lane >> 4;
    f32x4 acc[4][4] = {};
    const ushort_t* ag = A + (size_t)(bm * 128 + (tid >> 2)) * K + (tid & 3) * 8;
    const ushort_t* bg = Bt + (size_t)(bn * 128 + (tid >> 2)) * K + (tid & 3) * 8;
    ushort_t* asd = As + wid * 512;
    ushort_t* bsd = Bs + wid * 512;
    for (int kt = 0; kt < K / 32; ++kt) {
        __syncthreads();
        gload_lds16(ag + kt * 32, asd);
        gload_lds16(ag + (size_t)64 * K + kt * 32, asd + 2048);
        gload_lds16(bg + kt * 32, bsd);
        gload_lds16(bg + (size_t)64 * K + kt * 32, bsd + 2048);
        __syncthreads();
        bfrag a[4], b[4];
#pragma unroll
        for (int mi = 0; mi < 4; ++mi) a[mi] = *(const bfrag*)&As[(wm * 64 + mi * 16 + lm) * 32 + lg * 8];
#pragma unroll
        for (int ni = 0; ni < 4; ++ni) b[ni] = *(const bfrag*)&Bs[(wn * 64 + ni * 16 + lm) * 32 + lg * 8];
#pragma unroll
        for (int mi = 0; mi < 4; ++mi)
#pragma unroll
            for (int ni = 0; ni < 4; ++ni)
                acc[mi][ni] = __builtin_amdgcn_mfma_f32_16x16x32_bf16(a[mi], b[ni], acc[mi][ni], 0, 0, 0);
    }
    int cbase = bn * 128 + wn * 64;           // 64-col band = one head's D
    int sel = cbase >> 10;                    // 0=q 1=k 2=v
    int h = (cbase & 1023) >> 6;
    float b0 = bias[cbase + lm];
    float b1 = bias[cbase + 16 + lm];
    float b2 = bias[cbase + 32 + lm];
    float b3 = bias[cbase + 48 + lm];
    if (sel < 2) {
        ushort_t* dst = sel ? kw : qw;
        float scale = sel ? 1.0f : 0.18033688011112042f;  // q: 1/sqrt(64) * log2(e)
#pragma unroll
        for (int mi = 0; mi < 4; ++mi) {
#pragma unroll
            for (int i = 0; i < 4; ++i) {
                int r = bm * 128 + wm * 64 + mi * 16 + lg * 4 + i;
                int bb = r >> 11, tq = r & (T_ - 1);
                float2 cs0 = cstab[tq * 32 + lm];
                float2 cs1 = cstab[tq * 32 + 16 + lm];
                float x0 = acc[mi][0][i] + b0;
                float x1 = acc[mi][1][i] + b1;
                float x2 = acc[mi][2][i] + b2;
                float x3 = acc[mi][3][i] + b3;
                size_t base = ((size_t)(bb * H_ + h) * T_ + tq) * D_;
                dst[base + lm]      = f2b((x0 * cs0.x - x2 * cs0.y) * scale);
                dst[base + 32 + lm] = f2b((x2 * cs0.x + x0 * cs0.y) * scale);
                dst[base + 16 + lm] = f2b((x1 * cs1.x - x3 * cs1.y) * scale);
                dst[base + 48 + lm] = f2b((x3 * cs1.x + x1 * cs1.y) * scale);
            }
        }
    } else {
        float bb4[4] = {b0, b1, b2, b3};
#pragma unroll
        for (int ni = 0; ni < 4; ++ni) {
            int d = ni * 16 + lm;
#pragma unroll
            for (int mi = 0; mi < 4; ++mi) {
                int r = bm * 128 + wm * 64 + mi * 16 + lg * 4;
                int bb = r >> 11, tq = r & (T_ - 1);
                uint32_t lo = (uint32_t)f2b(acc[mi][ni][0] + bb4[ni]) | ((uint32_t)f2b(acc[mi][ni][1] + bb4[ni]) << 16);
                uint32_t hi = (uint32_t)f2b(acc[mi][ni][2] + bb4[ni]) | ((uint32_t)f2b(acc[mi][ni][3] + bb4[ni]) << 16);
                uint2 w; w.x = lo; w.y = hi;
                *(uint2*)&vw[((size_t)(bb * H_ + h) * D_ + d) * T_ + tq] = w;
            }
        }
    }
}

// ---------------- causal flash attention: no LDS, no barriers ----------------
// 16-row Q tasks; 4096 tasks -> 1024 blocks x 4 waves (16 waves/CU). All waves
// in a block share q-tile j (different bh) -> zero intra-block imbalance; j
// descending so long blocks dispatch first; blockIdx&7 pins bh-sets per XCD.
// Swapped QK^T (mfma(K,Q)): lane holds P column for q = q0+(lane&15) -> in-reg
// softmax (log2 domain), defer-max (THR=11.5), per-lane l-partial (reduce once
// at end), cvt_pk P->bf16, PV from transposed Vt with matching k-permutation.
__global__ __launch_bounds__(256) void flash_kernel(const ushort_t* __restrict__ q, const ushort_t* __restrict__ k,
                                                    const ushort_t* __restrict__ vt, ushort_t* __restrict__ o) {
    int tid = threadIdx.x, lane = tid & 63, wid = tid >> 6;
    int lm = lane & 15, lg = lane >> 4;
    int x = blockIdx.x & 7, l = blockIdx.x >> 3;
    int j = 127 - l;          // q-tile index, descending
    int bh = x * 4 + wid;
    int q0 = j << 4;
    int b = bh >> 4, h = bh & 15;
    int ntile = (j >> 1) + 1; // 32-key tiles

    const ushort_t* qb = q + (size_t)bh * T_ * D_;
    const ushort_t* kb = k + (size_t)bh * T_ * D_;
    const ushort_t* vb = vt + (size_t)bh * D_ * T_;

    bfrag aq[2];
    aq[0] = *(const bfrag*)(qb + (size_t)(q0 + lm) * D_ + lg * 8);
    aq[1] = *(const bfrag*)(qb + (size_t)(q0 + lm) * D_ + 32 + lg * 8);

    f32x4 acc[4] = {};
    float m_s = -1e30f;
    float lsum = 0.f;   // per-lane partial of softmax denominator

    bfrag ka[2][2];
#pragma unroll
    for (int sb = 0; sb < 2; ++sb)
#pragma unroll
        for (int hh = 0; hh < 2; ++hh)
            ka[sb][hh] = *(const bfrag*)(kb + (size_t)(sb * 16 + lm) * D_ + hh * 32 + lg * 8);

    for (int t = 0; t < ntile; ++t) {
        int k0 = t * 32;
        // V loads for this tile (latency hides under QK + softmax)
        s16x4 v0[4], v1[4];
#pragma unroll
        for (int db = 0; db < 4; ++db) {
            const ushort_t* vr = vb + (size_t)(db * 16 + lm) * T_ + k0 + lg * 4;
            v0[db] = *(const s16x4*)vr;
            v1[db] = *(const s16x4*)(vr + 16);
        }
        // swapped QK^T: st[sb][i] = S^T[k = k0+16sb+4lg+i][q = q0+lm] (log2 domain)
        f32x4 st[2];
        __builtin_amdgcn_s_setprio(1);
#pragma unroll
        for (int sb = 0; sb < 2; ++sb) {
            f32x4 z = {};
            z = __builtin_amdgcn_mfma_f32_16x16x32_bf16(ka[sb][0], aq[0], z, 0, 0, 0);
            st[sb] = __builtin_amdgcn_mfma_f32_16x16x32_bf16(ka[sb][1], aq[1], z, 0, 0, 0);
        }
        __builtin_amdgcn_s_setprio(0);
        // prefetch next K tile
        if (t + 1 < ntile) {
#pragma unroll
            for (int sb = 0; sb < 2; ++sb)
#pragma unroll
                for (int hh = 0; hh < 2; ++hh)
                    ka[sb][hh] = *(const bfrag*)(kb + (size_t)(k0 + 32 + sb * 16 + lm) * D_ + hh * 32 + lg * 8);
        }
        // causal mask, last tile only
        if (t == ntile - 1) {
#pragma unroll
            for (int sb = 0; sb < 2; ++sb)
#pragma unroll
                for (int i = 0; i < 4; ++i)
                    if (k0 + sb * 16 + lg * 4 + i > q0 + lm) st[sb][i] = -1e30f;
        }
        // column max (k spans the 4 lane-groups)
        float t0 = fmaxf(fmaxf(st[0][0], st[0][1]), fmaxf(st[0][2], st[0][3]));
        float t1 = fmaxf(fmaxf(st[1][0], st[1][1]), fmaxf(st[1][2], st[1][3]));
        float tm = fmaxf(t0, t1);
        tm = fmaxf(tm, __shfl_xor(tm, 16));
        tm = fmaxf(tm, __shfl_xor(tm, 32));
        // defer-max: rescale only when max grew by more than THR (log2 domain)
        if (!__all(tm <= m_s + 11.5f)) {
            float mnew = fmaxf(m_s, tm);
            float corr = EXP2(m_s - mnew);
#pragma unroll
            for (int db = 0; db < 4; ++db) acc[db] *= corr;
            lsum *= corr;
            m_s = mnew;
        }
        float p00 = EXP2(st[0][0] - m_s), p01 = EXP2(st[0][1] - m_s);
        float p02 = EXP2(st[0][2] - m_s), p03 = EXP2(st[0][3] - m_s);
        float p10 = EXP2(st[1][0] - m_s), p11 = EXP2(st[1][1] - m_s);
        float p12 = EXP2(st[1][2] - m_s), p13 = EXP2(st[1][3] - m_s);
        lsum += ((p00 + p01) + (p02 + p03)) + ((p10 + p11) + (p12 + p13));
        uint4 u4;
        u4.x = cvtpk_bf16(p00, p01);
        u4.y = cvtpk_bf16(p02, p03);
        u4.z = cvtpk_bf16(p10, p11);
        u4.w = cvtpk_bf16(p12, p13);
        bfrag pf = __builtin_bit_cast(bfrag, u4);
        // PV: acc^T[d][q] += V-frag * P-frag (shared k-slot permutation)
        __builtin_amdgcn_s_setprio(1);
#pragma unroll
        for (int db = 0; db < 4; ++db) {
            bfrag va = __builtin_shufflevector(v0[db], v1[db], 0, 1, 2, 3, 4, 5, 6, 7);
            acc[db] = __builtin_amdgcn_mfma_f32_16x16x32_bf16(va, pf, acc[db], 0, 0, 0);
        }
        __builtin_amdgcn_s_setprio(0);
    }
    // finish l reduce across the 4 lane-groups
    lsum += __shfl_xor(lsum, 16);
    lsum += __shfl_xor(lsum, 32);
    float inv = 1.0f / lsum;
    int tq = q0 + lm;
    size_t ro = ((size_t)b * T_ + tq) * E_ + h * D_;
#pragma unroll
    for (int db = 0; db < 4; ++db) {
        uint32_t lo = (uint32_t)f2b(acc[db][0] * inv) | ((uint32_t)f2b(acc[db][1] * inv) << 16);
        uint32_t hi = (uint32_t)f2b(acc[db][2] * inv) | ((uint32_t)f2b(acc[db][3] * inv) << 16);
        uint2 w; w.x = lo; w.y = hi;
        *(uint2*)(o + ro + db * 16 + lg * 4) = w;
    }
}

// ---------------- GEMM2: out = ao @ w_out + b_out (fp32 out) ----------------
__global__ __launch_bounds__(256) void gemm_out_kernel(const ushort_t* __restrict__ A, const ushort_t* __restrict__ Bt,
                                                       const float* __restrict__ bias, float* __restrict__ out) {
    const int K = 1024;
    __shared__ ushort_t As[128 * 32];
    __shared__ ushort_t Bs[128 * 32];
    int tid = threadIdx.x, lane = tid & 63, wid = tid >> 6;
    int bm = blockIdx.y, bn = blockIdx.x;
    int wm = wid >> 1, wn = wid & 1;
    int lm = lane & 15, lg = lane >> 4;
    f32x4 acc[4][4] = {};
    const ushort_t* ag = A + (size_t)(bm * 128 + (tid >> 2)) * K + (tid & 3) * 8;
    const ushort_t* bg = Bt + (size_t)(bn * 128 + (tid >> 2)) * K + (tid & 3) * 8;
    ushort_t* asd = As + wid * 512;
    ushort_t* bsd = Bs + wid * 512;
    for (int kt = 0; kt < K / 32; ++kt) {
        __syncthreads();
        gload_lds16(ag + kt * 32, asd);
        gload_lds16(ag + (size_t)64 * K + kt * 32, asd + 2048);
        gload_lds16(bg + kt * 32, bsd);
        gload_lds16(bg + (size_t)64 * K + kt * 32, bsd + 2048);
        __syncthreads();
        bfrag a[4], b[4];
#pragma unroll
        for (int mi = 0; mi < 4; ++mi) a[mi] = *(const bfrag*)&As[(wm * 64 + mi * 16 + lm) * 32 + lg * 8];
#pragma unroll
        for (int ni = 0; ni < 4; ++ni) b[ni] = *(const bfrag*)&Bs[(wn * 64 + ni * 16 + lm) * 32 + lg * 8];
#pragma unroll
        for (int mi = 0; mi < 4; ++mi)
#pragma unroll
            for (int ni = 0; ni < 4; ++ni)
                acc[mi][ni] = __builtin_amdgcn_mfma_f32_16x16x32_bf16(a[mi], b[ni], acc[mi][ni], 0, 0, 0);
    }
#pragma unroll
    for (int ni = 0; ni < 4; ++ni) {
        int c = bn * 128 + wn * 64 + ni * 16 + lm;
        float bb = bias[c];
#pragma unroll
        for (int mi = 0; mi < 4; ++mi) {
#pragma unroll
            for (int i = 0; i < 4; ++i) {
                int r = bm * 128 + wm * 64 + mi * 16 + lg * 4 + i;
                out[(size_t)r * 1024 + c] = acc[mi][ni][i] + bb;
            }
        }
    }
}

extern "C" void kernel_launch(void* const* d_in, const int* in_sizes, int n_in,
                              void* d_out, int out_size, void* d_ws, size_t ws_size,
                              hipStream_t stream) {
    const float* x     = (const float*)d_in[0];
    const float* w_qkv = (const float*)d_in[1];
    const float* b_qkv = (const float*)d_in[2];
    const float* w_out = (const float*)d_in[3];
    const float* b_out = (const float*)d_in[4];
    float* out = (float*)d_out;

    ushort_t* ws    = (ushort_t*)d_ws;
    ushort_t* xb    = ws;                   // [4096][1024] bf16
    ushort_t* wqkvT = xb + 4194304;         // [3072][1024] bf16
    ushort_t* woutT = wqkvT + 3145728;      // [1024][1024] bf16
    ushort_t* qw    = woutT + 1048576;      // [BH][T][D]
    ushort_t* kw    = qw + 4194304;
    ushort_t* vw    = kw + 4194304;         // Vt: [BH][D][T]
    ushort_t* ao    = vw + 4194304;         // [4096][1024] bf16
    float2*   cstab = (float2*)(ao + 4194304);  // [2048][32] (cos,sin) = 512 KB

    rope_table_kernel<<<256, 256, 0, stream>>>(cstab);
    cast_x_kernel<<<2048, 256, 0, stream>>>(x, xb);
    transpose_cast_kernel<<<dim3(96, 32), dim3(32, 8), 0, stream>>>(w_qkv, wqkvT, 1024, 3072);
    transpose_cast_kernel<<<dim3(32, 32), dim3(32, 8), 0, stream>>>(w_out, woutT, 1024, 1024);
    gemm_qkv_kernel<<<dim3(24, 32), 256, 0, stream>>>(xb, wqkvT, b_qkv, cstab, qw, kw, vw);
    flash_kernel<<<dim3(1024), 256, 0, stream>>>(qw, kw, vw, ao);
    gemm_out_kernel<<<dim3(8, 32), 256, 0, stream>>>(ao, woutT, b_out, out);
}

// Round 5
// 204.671 us; speedup vs baseline: 1.4962x; 1.4962x over previous
//
#include <hip/hip_runtime.h>
#include <hip/hip_bf16.h>
#include <stdint.h>

// Problem constants
#define B_  2
#define T_  2048
#define E_  1024
#define H_  16
#define D_  64
#define BH_ 32   // B_*H_

typedef unsigned short ushort_t;
typedef __attribute__((ext_vector_type(8))) short bfrag;   // 8 bf16 (4 VGPRs) MFMA A/B operand
typedef __attribute__((ext_vector_type(4))) short s16x4;   // 4 bf16 (8B)
typedef __attribute__((ext_vector_type(4))) float f32x4;   // MFMA C/D

__device__ __forceinline__ ushort_t f2b(float f) {  // fp32 -> bf16 (RTNE)
    uint32_t u = __builtin_bit_cast(uint32_t, f);
    u += 0x7fffu + ((u >> 16) & 1u);
    return (ushort_t)(u >> 16);
}
__device__ __forceinline__ float b2f(ushort_t h) {
    return __builtin_bit_cast(float, (uint32_t)h << 16);
}

#if defined(__has_builtin)
#if __has_builtin(__builtin_amdgcn_exp2f)
#define EXP2(x) __builtin_amdgcn_exp2f(x)
#endif
#endif
#ifndef EXP2
__device__ __forceinline__ float hexp2_(float x) {
    float r;
    asm volatile("v_exp_f32 %0, %1\n\ts_nop 1" : "=v"(r) : "v"(x));
    return r;
}
#define EXP2(x) hexp2_(x)
#endif

__device__ __forceinline__ uint32_t cvtpk_bf16(float lo, float hi) {
    uint32_t r;
    asm("v_cvt_pk_bf16_f32 %0, %1, %2" : "=v"(r) : "v"(lo), "v"(hi));
    return r;
}

typedef const __attribute__((address_space(1))) uint8_t* gas_t;
typedef __attribute__((address_space(3))) uint8_t* las_t;
__device__ __forceinline__ void gload_lds16(const void* g, void* l) {
    __builtin_amdgcn_global_load_lds((gas_t)g, (las_t)l, 16, 0, 0);
}

// ---------------- RoPE cos/sin table: cs[t][j] = (cos, sin), t<2048, j<32 ----------------
__global__ __launch_bounds__(256) void rope_table_kernel(float2* __restrict__ cs) {
    int id = blockIdx.x * 256 + threadIdx.x;  // 65536
    int j = id & 31, t = id >> 5;
    float ang = (float)t * expf(-(float)j * 0.2878231366242558f);  // ln(10000)/32
    float s, c;
    sincosf(ang, &s, &c);
    cs[id] = make_float2(c, s);
}

// ---------------- cast x fp32 -> bf16 ----------------
__global__ __launch_bounds__(256) void cast_x_kernel(const float* __restrict__ in, ushort_t* __restrict__ out) {
    int i = (blockIdx.x * 256 + threadIdx.x) * 8;
    float4 a = *(const float4*)(in + i);
    float4 b = *(const float4*)(in + i + 4);
    ushort_t r[8] = {f2b(a.x), f2b(a.y), f2b(a.z), f2b(a.w), f2b(b.x), f2b(b.y), f2b(b.z), f2b(b.w)};
    *(uint4*)(out + i) = *(const uint4*)r;
}

// ------------- transpose+cast: in[R][C] fp32 -> out[C][R] bf16 -------------
__global__ __launch_bounds__(256) void transpose_cast_kernel(const float* __restrict__ in, ushort_t* __restrict__ out,
                                                             int R, int C) {
    __shared__ float tile[32][33];
    int tx = threadIdx.x, ty = threadIdx.y;
    int c0 = blockIdx.x * 32, r0 = blockIdx.y * 32;
#pragma unroll
    for (int i = 0; i < 4; ++i)
        tile[ty + i * 8][tx] = in[(size_t)(r0 + ty + i * 8) * C + c0 + tx];
    __syncthreads();
#pragma unroll
    for (int i = 0; i < 4; ++i)
        out[(size_t)(c0 + ty + i * 8) * R + r0 + tx] = f2b(tile[tx][ty + i * 8]);
}

// ---------------- GEMM1: qkv = x @ w_qkv + b, fused RoPE on q,k ----------------
// q,k -> [BH][T][D] (rotated; q pre-scaled by 1/8*log2e);  v -> TRANSPOSED Vt [BH][D][T]
__global__ __launch_bounds__(256) void gemm_qkv_kernel(const ushort_t* __restrict__ A, const ushort_t* __restrict__ Bt,
                                                       const float* __restrict__ bias, const float2* __restrict__ cstab,
                                                       ushort_t* __restrict__ qw, ushort_t* __restrict__ kw,
                                                       ushort_t* __restrict__ vw) {
    const int K = 1024;
    __shared__ ushort_t As[128 * 32];
    __shared__ ushort_t Bs[128 * 32];
    int tid = threadIdx.x, lane = tid & 63, wid = tid >> 6;
    int bm = blockIdx.y, bn = blockIdx.x;
    int wm = wid >> 1, wn = wid & 1;
    int lm = lane & 15, lg = lane >> 4;
    f32x4 acc[4][4] = {};
    const ushort_t* ag = A + (size_t)(bm * 128 + (tid >> 2)) * K + (tid & 3) * 8;
    const ushort_t* bg = Bt + (size_t)(bn * 128 + (tid >> 2)) * K + (tid & 3) * 8;
    ushort_t* asd = As + wid * 512;
    ushort_t* bsd = Bs + wid * 512;
    for (int kt = 0; kt < K / 32; ++kt) {
        __syncthreads();
        gload_lds16(ag + kt * 32, asd);
        gload_lds16(ag + (size_t)64 * K + kt * 32, asd + 2048);
        gload_lds16(bg + kt * 32, bsd);
        gload_lds16(bg + (size_t)64 * K + kt * 32, bsd + 2048);
        __syncthreads();
        bfrag a[4], b[4];
#pragma unroll
        for (int mi = 0; mi < 4; ++mi) a[mi] = *(const bfrag*)&As[(wm * 64 + mi * 16 + lm) * 32 + lg * 8];
#pragma unroll
        for (int ni = 0; ni < 4; ++ni) b[ni] = *(const bfrag*)&Bs[(wn * 64 + ni * 16 + lm) * 32 + lg * 8];
#pragma unroll
        for (int mi = 0; mi < 4; ++mi)
#pragma unroll
            for (int ni = 0; ni < 4; ++ni)
                acc[mi][ni] = __builtin_amdgcn_mfma_f32_16x16x32_bf16(a[mi], b[ni], acc[mi][ni], 0, 0, 0);
    }
    int cbase = bn * 128 + wn * 64;           // 64-col band = one head's D
    int sel = cbase >> 10;                    // 0=q 1=k 2=v
    int h = (cbase & 1023) >> 6;
    float b0 = bias[cbase + lm];
    float b1 = bias[cbase + 16 + lm];
    float b2 = bias[cbase + 32 + lm];
    float b3 = bias[cbase + 48 + lm];
    if (sel < 2) {
        ushort_t* dst = sel ? kw : qw;
        float scale = sel ? 1.0f : 0.18033688011112042f;  // q: 1/sqrt(64) * log2(e)
#pragma unroll
        for (int mi = 0; mi < 4; ++mi) {
#pragma unroll
            for (int i = 0; i < 4; ++i) {
                int r = bm * 128 + wm * 64 + mi * 16 + lg * 4 + i;
                int bb = r >> 11, tq = r & (T_ - 1);
                float2 cs0 = cstab[tq * 32 + lm];
                float2 cs1 = cstab[tq * 32 + 16 + lm];
                float x0 = acc[mi][0][i] + b0;
                float x1 = acc[mi][1][i] + b1;
                float x2 = acc[mi][2][i] + b2;
                float x3 = acc[mi][3][i] + b3;
                size_t base = ((size_t)(bb * H_ + h) * T_ + tq) * D_;
                dst[base + lm]      = f2b((x0 * cs0.x - x2 * cs0.y) * scale);
                dst[base + 32 + lm] = f2b((x2 * cs0.x + x0 * cs0.y) * scale);
                dst[base + 16 + lm] = f2b((x1 * cs1.x - x3 * cs1.y) * scale);
                dst[base + 48 + lm] = f2b((x3 * cs1.x + x1 * cs1.y) * scale);
            }
        }
    } else {
        float bb4[4] = {b0, b1, b2, b3};
#pragma unroll
        for (int ni = 0; ni < 4; ++ni) {
            int d = ni * 16 + lm;
#pragma unroll
            for (int mi = 0; mi < 4; ++mi) {
                int r = bm * 128 + wm * 64 + mi * 16 + lg * 4;
                int bb = r >> 11, tq = r & (T_ - 1);
                uint32_t lo = (uint32_t)f2b(acc[mi][ni][0] + bb4[ni]) | ((uint32_t)f2b(acc[mi][ni][1] + bb4[ni]) << 16);
                uint32_t hi = (uint32_t)f2b(acc[mi][ni][2] + bb4[ni]) | ((uint32_t)f2b(acc[mi][ni][3] + bb4[ni]) << 16);
                uint2 w; w.x = lo; w.y = hi;
                *(uint2*)&vw[((size_t)(bb * H_ + h) * D_ + d) * T_ + tq] = w;
            }
        }
    }
}

// ---------------- causal flash attention: split-K, no staging LDS ----------------
// 32-row Q tasks (2048); each task processed by TWO waves (even/odd 32-key tiles),
// merged once at the end through LDS (per-ROW maxes: mbuf[task][s][16]).
// 1024 blocks x 4 waves = 16 waves/CU; all 4 waves in a block share qt.
__global__ __launch_bounds__(256, 4) void flash_kernel(const ushort_t* __restrict__ q, const ushort_t* __restrict__ k,
                                                       const ushort_t* __restrict__ vt, ushort_t* __restrict__ o) {
    __shared__ float accbuf[2][2048];   // [task][lane*32 + swizzled slot*4]
    __shared__ float lbuf[2][2][64];    // [task][s][lane]
    __shared__ float mbuf[2][2][16];    // [task][s][lm]  (per-q-row running max!)
    int tid = threadIdx.x, lane = tid & 63, wid = tid >> 6;
    int lm = lane & 15, lg = lane >> 4;
    int x = blockIdx.x & 7, bl = blockIdx.x >> 3;
    int task = wid >> 1, p = wid & 1;   // p: key-tile parity this wave handles
    int qt = 63 - (bl >> 1);            // 32-row q-tile index, descending
    int bh = x * 4 + (bl & 1) * 2 + task;
    int q0 = qt << 5;
    int b = bh >> 4, h = bh & 15;
    int ntile = qt + 1;                 // 32-key tiles

    const ushort_t* qb = q + (size_t)bh * T_ * D_;
    const ushort_t* kb = k + (size_t)bh * T_ * D_;
    const ushort_t* vb = vt + (size_t)bh * D_ * T_;

    bfrag aq[2][2];
#pragma unroll
    for (int s = 0; s < 2; ++s)
#pragma unroll
        for (int hh = 0; hh < 2; ++hh)
            aq[s][hh] = *(const bfrag*)(qb + (size_t)(q0 + s * 16 + lm) * D_ + hh * 32 + lg * 8);

    f32x4 acc[2][4] = {};
    float m_s[2] = {-1e30f, -1e30f};
    float lsum[2] = {0.f, 0.f};

    bfrag ka[2][2];
    if (p < ntile) {
#pragma unroll
        for (int sb = 0; sb < 2; ++sb)
#pragma unroll
            for (int hh = 0; hh < 2; ++hh)
                ka[sb][hh] = *(const bfrag*)(kb + (size_t)(p * 32 + sb * 16 + lm) * D_ + hh * 32 + lg * 8);
    }

    for (int t = p; t < ntile; t += 2) {
        int k0 = t * 32;
        // V loads for this tile (latency hides under QK + softmax)
        s16x4 v0[4], v1[4];
#pragma unroll
        for (int db = 0; db < 4; ++db) {
            const ushort_t* vr = vb + (size_t)(db * 16 + lm) * T_ + k0 + lg * 4;
            v0[db] = *(const s16x4*)vr;
            v1[db] = *(const s16x4*)(vr + 16);
        }
        // swapped QK^T: st[s][sb][i] = S^T[k = k0+16sb+4lg+i][q = q0+16s+lm] (log2 domain)
        f32x4 st[2][2];
        __builtin_amdgcn_s_setprio(1);
#pragma unroll
        for (int s = 0; s < 2; ++s)
#pragma unroll
            for (int sb = 0; sb < 2; ++sb) {
                f32x4 z = {};
                z = __builtin_amdgcn_mfma_f32_16x16x32_bf16(ka[sb][0], aq[s][0], z, 0, 0, 0);
                st[s][sb] = __builtin_amdgcn_mfma_f32_16x16x32_bf16(ka[sb][1], aq[s][1], z, 0, 0, 0);
            }
        __builtin_amdgcn_s_setprio(0);
        // prefetch this wave's next K tile (t+2)
        if (t + 2 < ntile) {
#pragma unroll
            for (int sb = 0; sb < 2; ++sb)
#pragma unroll
                for (int hh = 0; hh < 2; ++hh)
                    ka[sb][hh] = *(const bfrag*)(kb + (size_t)(k0 + 64 + sb * 16 + lm) * D_ + hh * 32 + lg * 8);
        }
        // causal mask (diagonal tile only)
        if (t == ntile - 1) {
#pragma unroll
            for (int s = 0; s < 2; ++s)
#pragma unroll
                for (int sb = 0; sb < 2; ++sb)
#pragma unroll
                    for (int i = 0; i < 4; ++i)
                        if (k0 + sb * 16 + lg * 4 + i > q0 + s * 16 + lm) st[s][sb][i] = -1e30f;
        }
        bfrag pf[2];
#pragma unroll
        for (int s = 0; s < 2; ++s) {
            float t0 = fmaxf(fmaxf(st[s][0][0], st[s][0][1]), fmaxf(st[s][0][2], st[s][0][3]));
            float t1 = fmaxf(fmaxf(st[s][1][0], st[s][1][1]), fmaxf(st[s][1][2], st[s][1][3]));
            float tm = fmaxf(t0, t1);
            tm = fmaxf(tm, __shfl_xor(tm, 16));
            tm = fmaxf(tm, __shfl_xor(tm, 32));
            // defer-max: rescale only when max grew by more than THR (log2 domain)
            if (!__all(tm <= m_s[s] + 11.5f)) {
                float mnew = fmaxf(m_s[s], tm);
                float corr = EXP2(m_s[s] - mnew);
#pragma unroll
                for (int db = 0; db < 4; ++db) acc[s][db] *= corr;
                lsum[s] *= corr;
                m_s[s] = mnew;
            }
            float p00 = EXP2(st[s][0][0] - m_s[s]), p01 = EXP2(st[s][0][1] - m_s[s]);
            float p02 = EXP2(st[s][0][2] - m_s[s]), p03 = EXP2(st[s][0][3] - m_s[s]);
            float p10 = EXP2(st[s][1][0] - m_s[s]), p11 = EXP2(st[s][1][1] - m_s[s]);
            float p12 = EXP2(st[s][1][2] - m_s[s]), p13 = EXP2(st[s][1][3] - m_s[s]);
            lsum[s] += ((p00 + p01) + (p02 + p03)) + ((p10 + p11) + (p12 + p13));
            uint4 u4;
            u4.x = cvtpk_bf16(p00, p01);
            u4.y = cvtpk_bf16(p02, p03);
            u4.z = cvtpk_bf16(p10, p11);
            u4.w = cvtpk_bf16(p12, p13);
            pf[s] = __builtin_bit_cast(bfrag, u4);
        }
        // PV: acc^T[d][q] += V-frag * P-frag (shared k-slot permutation)
        __builtin_amdgcn_s_setprio(1);
#pragma unroll
        for (int s = 0; s < 2; ++s)
#pragma unroll
            for (int db = 0; db < 4; ++db) {
                bfrag va = __builtin_shufflevector(v0[db], v1[db], 0, 1, 2, 3, 4, 5, 6, 7);
                acc[s][db] = __builtin_amdgcn_mfma_f32_16x16x32_bf16(va, pf[s], acc[s][db], 0, 0, 0);
            }
        __builtin_amdgcn_s_setprio(0);
    }

    // ---- split-K combine through LDS ----
    if (p == 0) {
#pragma unroll
        for (int s = 0; s < 2; ++s)
#pragma unroll
            for (int db = 0; db < 4; ++db)
                *(f32x4*)&accbuf[task][lane * 32 + (((s * 4 + db) ^ (lane & 7)) << 2)] = acc[s][db];
        lbuf[task][0][lane] = lsum[0];
        lbuf[task][1][lane] = lsum[1];
        if (lg == 0) {                      // one writer per q row
            mbuf[task][0][lm] = m_s[0];
            mbuf[task][1][lm] = m_s[1];
        }
    }
    __syncthreads();
    if (p == 1) {
#pragma unroll
        for (int s = 0; s < 2; ++s) {
            float mA = mbuf[task][s][lm];   // per-row max of partner wave
            float mM = fmaxf(mA, m_s[s]);
            float cA = EXP2(mA - mM);
            float cB = EXP2(m_s[s] - mM);
            float lM = cA * lbuf[task][s][lane] + cB * lsum[s];
            lM += __shfl_xor(lM, 16);
            lM += __shfl_xor(lM, 32);
            float inv = 1.0f / lM;
            int tq = q0 + s * 16 + lm;
            size_t ro = ((size_t)b * T_ + tq) * E_ + h * D_;
#pragma unroll
            for (int db = 0; db < 4; ++db) {
                f32x4 aA = *(const f32x4*)&accbuf[task][lane * 32 + (((s * 4 + db) ^ (lane & 7)) << 2)];
                float r0 = (aA[0] * cA + acc[s][db][0] * cB) * inv;
                float r1 = (aA[1] * cA + acc[s][db][1] * cB) * inv;
                float r2 = (aA[2] * cA + acc[s][db][2] * cB) * inv;
                float r3 = (aA[3] * cA + acc[s][db][3] * cB) * inv;
                uint2 w;
                w.x = cvtpk_bf16(r0, r1);
                w.y = cvtpk_bf16(r2, r3);
                *(uint2*)(o + ro + db * 16 + lg * 4) = w;
            }
        }
    }
}

// ---------------- GEMM2: out = ao @ w_out + b_out (fp32 out) ----------------
__global__ __launch_bounds__(256) void gemm_out_kernel(const ushort_t* __restrict__ A, const ushort_t* __restrict__ Bt,
                                                       const float* __restrict__ bias, float* __restrict__ out) {
    const int K = 1024;
    __shared__ ushort_t As[128 * 32];
    __shared__ ushort_t Bs[128 * 32];
    int tid = threadIdx.x, lane = tid & 63, wid = tid >> 6;
    int bm = blockIdx.y, bn = blockIdx.x;
    int wm = wid >> 1, wn = wid & 1;
    int lm = lane & 15, lg = lane >> 4;
    f32x4 acc[4][4] = {};
    const ushort_t* ag = A + (size_t)(bm * 128 + (tid >> 2)) * K + (tid & 3) * 8;
    const ushort_t* bg = Bt + (size_t)(bn * 128 + (tid >> 2)) * K + (tid & 3) * 8;
    ushort_t* asd = As + wid * 512;
    ushort_t* bsd = Bs + wid * 512;
    for (int kt = 0; kt < K / 32; ++kt) {
        __syncthreads();
        gload_lds16(ag + kt * 32, asd);
        gload_lds16(ag + (size_t)64 * K + kt * 32, asd + 2048);
        gload_lds16(bg + kt * 32, bsd);
        gload_lds16(bg + (size_t)64 * K + kt * 32, bsd + 2048);
        __syncthreads();
        bfrag a[4], b[4];
#pragma unroll
        for (int mi = 0; mi < 4; ++mi) a[mi] = *(const bfrag*)&As[(wm * 64 + mi * 16 + lm) * 32 + lg * 8];
#pragma unroll
        for (int ni = 0; ni < 4; ++ni) b[ni] = *(const bfrag*)&Bs[(wn * 64 + ni * 16 + lm) * 32 + lg * 8];
#pragma unroll
        for (int mi = 0; mi < 4; ++mi)
#pragma unroll
            for (int ni = 0; ni < 4; ++ni)
                acc[mi][ni] = __builtin_amdgcn_mfma_f32_16x16x32_bf16(a[mi], b[ni], acc[mi][ni], 0, 0, 0);
    }
#pragma unroll
    for (int ni = 0; ni < 4; ++ni) {
        int c = bn * 128 + wn * 64 + ni * 16 + lm;
        float bb = bias[c];
#pragma unroll
        for (int mi = 0; mi < 4; ++mi) {
#pragma unroll
            for (int i = 0; i < 4; ++i) {
                int r = bm * 128 + wm * 64 + mi * 16 + lg * 4 + i;
                out[(size_t)r * 1024 + c] = acc[mi][ni][i] + bb;
            }
        }
    }
}

extern "C" void kernel_launch(void* const* d_in, const int* in_sizes, int n_in,
                              void* d_out, int out_size, void* d_ws, size_t ws_size,
                              hipStream_t stream) {
    const float* x     = (const float*)d_in[0];
    const float* w_qkv = (const float*)d_in[1];
    const float* b_qkv = (const float*)d_in[2];
    const float* w_out = (const float*)d_in[3];
    const float* b_out = (const float*)d_in[4];
    float* out = (float*)d_out;

    ushort_t* ws    = (ushort_t*)d_ws;
    ushort_t* xb    = ws;                   // [4096][1024] bf16
    ushort_t* wqkvT = xb + 4194304;         // [3072][1024] bf16
    ushort_t* woutT = wqkvT + 3145728;      // [1024][1024] bf16
    ushort_t* qw    = woutT + 1048576;      // [BH][T][D]
    ushort_t* kw    = qw + 4194304;
    ushort_t* vw    = kw + 4194304;         // Vt: [BH][D][T]
    ushort_t* ao    = vw + 4194304;         // [4096][1024] bf16
    float2*   cstab = (float2*)(ao + 4194304);  // [2048][32] (cos,sin) = 512 KB

    rope_table_kernel<<<256, 256, 0, stream>>>(cstab);
    cast_x_kernel<<<2048, 256, 0, stream>>>(x, xb);
    transpose_cast_kernel<<<dim3(96, 32), dim3(32, 8), 0, stream>>>(w_qkv, wqkvT, 1024, 3072);
    transpose_cast_kernel<<<dim3(32, 32), dim3(32, 8), 0, stream>>>(w_out, woutT, 1024, 1024);
    gemm_qkv_kernel<<<dim3(24, 32), 256, 0, stream>>>(xb, wqkvT, b_qkv, cstab, qw, kw, vw);
    flash_kernel<<<dim3(1024), 256, 0, stream>>>(qw, kw, vw, ao);
    gemm_out_kernel<<<dim3(8, 32), 256, 0, stream>>>(ao, woutT, b_out, out);
}